// Round 1
// baseline (61.720 us; speedup 1.0000x reference)
//
#include <hip/hip_runtime.h>
#include <hip/hip_bf16.h>
#include <stdint.h>

// SimCLR loss, n=8192, d=128, T=0.07.
// Pipeline:
//  k_normalize: fp32 features -> row-L2-normalized bf16 matrix fn (ws, 2 MiB)
//  k_simexp:    E_part[slice][row] = sum_{j in slice} exp2((dot_ij - 1)*s)   (MFMA bf16)
//               (includes diagonal; s = log2(e)/T; constant max-shift since cos<=1)
//  k_finalize:  per row: E = sum_slices - exp2((selfdot-1)*s);
//               term = 1/T + ln(E) - posdot/T
//  k_reduce:    mean over rows -> d_out[0]

#define N_ROWS 8192
#define DIM    128
#define HALF_N 4096
#define N_SLICES 16
#define JCOLS (N_ROWS / N_SLICES)      // 512 columns per j-slice
#define ROWS_PER_WAVE 64
#define ROWS_PER_BLOCK 256             // 4 waves * 64 rows

static constexpr float INV_T = 14.285714285714286f;   // 1/0.07
static constexpr float SCALE = 20.60992915555662f;    // log2(e)/0.07

typedef __attribute__((ext_vector_type(8))) short short8;   // 8 bf16 (4 VGPR)
typedef __attribute__((ext_vector_type(4))) float f32x4;

__device__ inline float bf_lo(uint32_t u) { return __uint_as_float(u << 16); }
__device__ inline float bf_hi(uint32_t u) { return __uint_as_float(u & 0xFFFF0000u); }
__device__ inline uint16_t f2bf(float x) {
    uint32_t u = __float_as_uint(x);
    return (uint16_t)((u + 0x7FFFu + ((u >> 16) & 1u)) >> 16);   // RNE
}

// ---------------- kernel 1: row L2-normalize, fp32 -> bf16 ----------------
__global__ __launch_bounds__(256) void k_normalize(const float* __restrict__ f,
                                                   uint16_t* __restrict__ fn) {
    int wid  = (blockIdx.x * blockDim.x + threadIdx.x) >> 6;   // one wave per row
    int lane = threadIdx.x & 63;
    const float2* src = (const float2*)(f + (size_t)wid * DIM);
    float2 v = src[lane];
    float ss = v.x * v.x + v.y * v.y;
    #pragma unroll
    for (int m = 1; m < 64; m <<= 1) ss += __shfl_xor(ss, m, 64);
    float inv = rsqrtf(ss);
    ushort2 o;
    o.x = f2bf(v.x * inv);
    o.y = f2bf(v.y * inv);
    ((ushort2*)(fn + (size_t)wid * DIM))[lane] = o;
}

// ---------------- kernel 2: fused sim + exp-sum (MFMA) ----------------
// Block: 256 threads = 4 waves; each wave owns 64 rows, block owns 256 rows.
// Grid: (N_ROWS/ROWS_PER_BLOCK, N_SLICES). Each block covers one j-slice of 512 cols.
__global__ __launch_bounds__(256) void k_simexp(const uint16_t* __restrict__ fn,
                                                float* __restrict__ E_part) {
    int lane = threadIdx.x & 63;
    int w    = threadIdx.x >> 6;
    int ib   = blockIdx.x * ROWS_PER_BLOCK + w * ROWS_PER_WAVE;
    int slice = blockIdx.y;
    int j0base = slice * JCOLS;
    int lr = lane & 15;       // row/col within fragment
    int lk = lane >> 4;       // k-group

    const short8* fn8 = (const short8*)fn;
    // fragment for row R, k-chunk kc: elements R*128 + kc*32 + lk*8 .. +8
    short8 Af[4][4];
    #pragma unroll
    for (int mt = 0; mt < 4; ++mt)
        #pragma unroll
        for (int kc = 0; kc < 4; ++kc)
            Af[mt][kc] = fn8[(size_t)(ib + mt * 16 + lr) * 16 + kc * 4 + lk];

    float es[4][4];
    #pragma unroll
    for (int mt = 0; mt < 4; ++mt)
        #pragma unroll
        for (int r = 0; r < 4; ++r) es[mt][r] = 0.0f;

    for (int jt = 0; jt < JCOLS / 16; ++jt) {
        int j0 = j0base + jt * 16;
        short8 Bf[4];
        #pragma unroll
        for (int kc = 0; kc < 4; ++kc)
            Bf[kc] = fn8[(size_t)(j0 + lr) * 16 + kc * 4 + lk];
        #pragma unroll
        for (int mt = 0; mt < 4; ++mt) {
            f32x4 acc = {0.0f, 0.0f, 0.0f, 0.0f};
            #pragma unroll
            for (int kc = 0; kc < 4; ++kc)
                acc = __builtin_amdgcn_mfma_f32_16x16x32_bf16(Af[mt][kc], Bf[kc], acc, 0, 0, 0);
            // epilogue: exp2((dot-1)*s), no branches (diagonal handled in finalize)
            #pragma unroll
            for (int r = 0; r < 4; ++r)
                es[mt][r] += exp2f(fmaf(acc[r], SCALE, -SCALE));
        }
    }

    // C/D layout: col = lane&15, row = (lane>>4)*4 + reg.
    // Sum over the 16 col-lanes (xor masks 1,2,4,8 within low 4 bits).
    #pragma unroll
    for (int mt = 0; mt < 4; ++mt)
        #pragma unroll
        for (int r = 0; r < 4; ++r) {
            float v = es[mt][r];
            v += __shfl_xor(v, 1, 64);
            v += __shfl_xor(v, 2, 64);
            v += __shfl_xor(v, 4, 64);
            v += __shfl_xor(v, 8, 64);
            if (lr == 0)
                E_part[(size_t)slice * N_ROWS + ib + mt * 16 + lk * 4 + r] = v;
        }
}

// ---------------- kernel 3: per-row finalize ----------------
__global__ __launch_bounds__(256) void k_finalize(const uint16_t* __restrict__ fn,
                                                  const float* __restrict__ E_part,
                                                  float* __restrict__ terms) {
    int wid  = (blockIdx.x * blockDim.x + threadIdx.x) >> 6;   // one wave per row
    int lane = threadIdx.x & 63;
    int partner = (wid + HALF_N) & (N_ROWS - 1);
    const uint32_t* fr = (const uint32_t*)(fn + (size_t)wid * DIM);
    const uint32_t* pr = (const uint32_t*)(fn + (size_t)partner * DIM);
    uint32_t a = fr[lane], p = pr[lane];
    float a0 = bf_lo(a), a1 = bf_hi(a);
    float p0 = bf_lo(p), p1 = bf_hi(p);
    float sd = a0 * a0 + a1 * a1;       // self dot (bf16 values, fp32 accum)
    float pd = a0 * p0 + a1 * p1;       // positive-pair dot
    #pragma unroll
    for (int m = 1; m < 64; m <<= 1) {
        sd += __shfl_xor(sd, m, 64);
        pd += __shfl_xor(pd, m, 64);
    }
    float e = (lane < N_SLICES) ? E_part[(size_t)lane * N_ROWS + wid] : 0.0f;
    #pragma unroll
    for (int m = 1; m < 64; m <<= 1) e += __shfl_xor(e, m, 64);
    if (lane == 0) {
        float ep = e - exp2f(fmaf(sd, SCALE, -SCALE));   // remove diagonal term
        terms[wid] = INV_T + logf(ep) - pd * INV_T;      // lse - pos
    }
}

// ---------------- kernel 4: mean ----------------
__global__ __launch_bounds__(256) void k_reduce(const float* __restrict__ terms,
                                                float* __restrict__ out) {
    __shared__ float sm[4];
    float acc = 0.0f;
    for (int i = threadIdx.x; i < N_ROWS; i += 256) acc += terms[i];
    #pragma unroll
    for (int m = 1; m < 64; m <<= 1) acc += __shfl_xor(acc, m, 64);
    if ((threadIdx.x & 63) == 0) sm[threadIdx.x >> 6] = acc;
    __syncthreads();
    if (threadIdx.x == 0)
        out[0] = (sm[0] + sm[1] + sm[2] + sm[3]) * (1.0f / N_ROWS);
}

extern "C" void kernel_launch(void* const* d_in, const int* in_sizes, int n_in,
                              void* d_out, int out_size, void* d_ws, size_t ws_size,
                              hipStream_t stream) {
    const float* feat = (const float*)d_in[0];
    float* out = (float*)d_out;

    // ws layout: fn (bf16, 2 MiB) | E_part (f32, 16*8192 = 512 KiB) | terms (f32, 32 KiB)
    uint16_t* fn  = (uint16_t*)d_ws;
    float* E_part = (float*)((char*)d_ws + (size_t)N_ROWS * DIM * 2);
    float* terms  = (float*)((char*)d_ws + (size_t)N_ROWS * DIM * 2 + (size_t)N_SLICES * N_ROWS * 4);

    k_normalize<<<dim3(N_ROWS / 4), dim3(256), 0, stream>>>(feat, fn);
    k_simexp<<<dim3(N_ROWS / ROWS_PER_BLOCK, N_SLICES), dim3(256), 0, stream>>>(fn, E_part);
    k_finalize<<<dim3(N_ROWS / 4), dim3(256), 0, stream>>>(fn, E_part, terms);
    k_reduce<<<dim3(1), dim3(256), 0, stream>>>(terms, out);
}